// Round 1
// baseline (916.444 us; speedup 1.0000x reference)
//
#include <hip/hip_runtime.h>

#define N_NODES  100000
#define N_EDGES  1000000
#define E_TOT    1100000   // edges + self-loops
#define N_GRAPHS 64

__device__ __forceinline__ float elu_f(float v) {
    return v > 0.f ? v : expm1f(v);
}

// ---------------------------------------------------------------------------
// K1: h1[n,c] = x[n,:4] . W1[c,:4]  (c = head*64+d, 128 cols)
//     as1[n,h] = sum_d h1[n,h,d]*att_src1[h,d];  ad1 likewise
// ---------------------------------------------------------------------------
__global__ void k_h1(const float* __restrict__ x, const float* __restrict__ w1,
                     const float* __restrict__ asrc, const float* __restrict__ adst,
                     float* __restrict__ h1, float* __restrict__ as1, float* __restrict__ ad1)
{
    __shared__ __align__(16) float sw[128 * 4];
    __shared__ float ssrc[128], sdst[128];
    for (int i = threadIdx.x; i < 512; i += blockDim.x) sw[i] = w1[i];
    for (int i = threadIdx.x; i < 128; i += blockDim.x) { ssrc[i] = asrc[i]; sdst[i] = adst[i]; }
    __syncthreads();

    int t = blockIdx.x * blockDim.x + threadIdx.x;   // grid sized exactly N*128
    int n = t >> 7, c = t & 127;
    const float4 xv = ((const float4*)x)[n];
    const float4 wv = ((const float4*)sw)[c];
    float h = xv.x * wv.x + xv.y * wv.y + xv.z * wv.z + xv.w * wv.w;
    h1[t] = h;

    float ps = h * ssrc[c];
    float pd = h * sdst[c];
    #pragma unroll
    for (int off = 32; off >= 1; off >>= 1) {
        ps += __shfl_xor(ps, off, 64);
        pd += __shfl_xor(pd, off, 64);
    }
    if ((c & 63) == 0) {
        int head = c >> 6;
        as1[n * 2 + head] = ps;
        ad1[n * 2 + head] = pd;
    }
}

// ---------------------------------------------------------------------------
// CSR build: count (with position capture), scan, scatter
// ---------------------------------------------------------------------------
__global__ void k_count(const int* __restrict__ ei, int* __restrict__ deg, int* __restrict__ pos)
{
    int e = blockIdx.x * blockDim.x + threadIdx.x;
    if (e >= E_TOT) return;
    int dst = (e < N_EDGES) ? ei[N_EDGES + e] : (e - N_EDGES);
    pos[e] = atomicAdd(&deg[dst], 1);
}

__global__ void k_scan1(const int* __restrict__ deg, int* __restrict__ ex, int* __restrict__ bsum)
{
    __shared__ int sh[256];
    int tid = threadIdx.x;
    int i = blockIdx.x * 256 + tid;
    int v = (i < N_NODES) ? deg[i] : 0;
    int acc = v;
    sh[tid] = acc; __syncthreads();
    for (int off = 1; off < 256; off <<= 1) {
        int add = (tid >= off) ? sh[tid - off] : 0;
        __syncthreads();
        acc += add;
        sh[tid] = acc;
        __syncthreads();
    }
    if (i < N_NODES) ex[i] = acc - v;          // block-local exclusive
    if (tid == 255) bsum[blockIdx.x] = acc;    // block total
}

__global__ void k_scan2(int* __restrict__ bsum, int nb)
{
    __shared__ int sh[512];
    int tid = threadIdx.x;
    int v = (tid < nb) ? bsum[tid] : 0;
    int acc = v;
    sh[tid] = acc; __syncthreads();
    for (int off = 1; off < 512; off <<= 1) {
        int add = (tid >= off) ? sh[tid - off] : 0;
        __syncthreads();
        acc += add;
        sh[tid] = acc;
        __syncthreads();
    }
    if (tid < nb) bsum[tid] = acc - v;         // exclusive block offsets
}

__global__ void k_scan3(int* __restrict__ rowptr, const int* __restrict__ bsum)
{
    int i = blockIdx.x * 256 + threadIdx.x;
    if (i < N_NODES) rowptr[i] += bsum[blockIdx.x];
    if (i == 0) rowptr[N_NODES] = E_TOT;
}

__global__ void k_scatter(const int* __restrict__ ei, const int* __restrict__ rowptr,
                          const int* __restrict__ pos, int* __restrict__ perm)
{
    int e = blockIdx.x * blockDim.x + threadIdx.x;
    if (e >= E_TOT) return;
    int dst = (e < N_EDGES) ? ei[N_EDGES + e] : (e - N_EDGES);
    perm[rowptr[dst] + pos[e]] = e;
}

// ---------------------------------------------------------------------------
// Gather layer 1: block = 128 threads per node (2 heads x 64 dims)
// ---------------------------------------------------------------------------
__global__ void __launch_bounds__(128) k_gather1(
    const int* __restrict__ ei, const int* __restrict__ rowptr, const int* __restrict__ perm,
    const float* __restrict__ h1, const float* __restrict__ as1, const float* __restrict__ ad1,
    const float* __restrict__ b1, float* __restrict__ out1)
{
    int n = blockIdx.x;
    int c = threadIdx.x;
    int head = c >> 6;
    int beg = rowptr[n], end = rowptr[n + 1];
    float adv = ad1[n * 2 + head];
    float acc = 0.f, wsum = 0.f;
    for (int j = beg; j < end; ++j) {
        int e = perm[j];
        int s = (e < N_EDGES) ? ei[e] : (e - N_EDGES);
        float ev = as1[s * 2 + head] + adv;
        ev = ev > 0.f ? ev : 0.2f * ev;        // leaky_relu
        float w = expf(ev);                    // softmax numerator (max-shift skipped; |e| < ~3)
        wsum += w;
        acc  += w * h1[s * 128 + c];
    }
    out1[n * 128 + c] = elu_f(acc / wsum + b1[c]);
}

// ---------------------------------------------------------------------------
// K-h2: h2[n,d] = out1[n,:128] . W2[d,:128]; plus as2/ad2 reductions
// W2 stored transposed in LDS to avoid stride-128 bank conflicts
// ---------------------------------------------------------------------------
__global__ void k_h2(const float* __restrict__ out1, const float* __restrict__ w2,
                     const float* __restrict__ asrc, const float* __restrict__ adst,
                     float* __restrict__ h2, float* __restrict__ as2, float* __restrict__ ad2)
{
    __shared__ float w2t[128 * 64];            // w2t[k*64+d] = w2[d*128+k]
    __shared__ float ssrc[64], sdst[64];
    for (int i = threadIdx.x; i < 8192; i += blockDim.x) {
        int d = i >> 7, k = i & 127;
        w2t[k * 64 + d] = w2[i];
    }
    for (int i = threadIdx.x; i < 64; i += blockDim.x) { ssrc[i] = asrc[i]; sdst[i] = adst[i]; }
    __syncthreads();

    int t = blockIdx.x * blockDim.x + threadIdx.x;  // grid sized exactly N*64
    int n = t >> 6, d = t & 63;
    const float* row = out1 + n * 128;
    float acc = 0.f;
    #pragma unroll 8
    for (int k = 0; k < 128; ++k) acc += row[k] * w2t[k * 64 + d];
    h2[t] = acc;

    float ps = acc * ssrc[d], pd = acc * sdst[d];
    #pragma unroll
    for (int off = 32; off >= 1; off >>= 1) {
        ps += __shfl_xor(ps, off, 64);
        pd += __shfl_xor(pd, off, 64);
    }
    if (d == 0) { as2[n] = ps; ad2[n] = pd; }
}

// ---------------------------------------------------------------------------
// Gather layer 2: 1 wave per node (64 dims, 1 head)
// ---------------------------------------------------------------------------
__global__ void __launch_bounds__(64) k_gather2(
    const int* __restrict__ ei, const int* __restrict__ rowptr, const int* __restrict__ perm,
    const float* __restrict__ h2, const float* __restrict__ as2, const float* __restrict__ ad2,
    const float* __restrict__ b2, float* __restrict__ out2)
{
    int n = blockIdx.x, d = threadIdx.x;
    int beg = rowptr[n], end = rowptr[n + 1];
    float adv = ad2[n];
    float acc = 0.f, wsum = 0.f;
    for (int j = beg; j < end; ++j) {
        int e = perm[j];
        int s = (e < N_EDGES) ? ei[e] : (e - N_EDGES);
        float ev = as2[s] + adv;
        ev = ev > 0.f ? ev : 0.2f * ev;
        float w = expf(ev);
        wsum += w;
        acc  += w * h2[s * 64 + d];
    }
    out2[n * 64 + d] = elu_f(acc / wsum + b2[d]);
}

// ---------------------------------------------------------------------------
// Global mean pool: LDS partial sums per block, then few global atomics
// ---------------------------------------------------------------------------
__global__ void k_pool(const float* __restrict__ out2, const int* __restrict__ batch,
                       float* __restrict__ pool, float* __restrict__ cnt)
{
    __shared__ float sp[N_GRAPHS * 64];
    __shared__ float sc[N_GRAPHS];
    for (int i = threadIdx.x; i < N_GRAPHS * 64; i += blockDim.x) sp[i] = 0.f;
    for (int i = threadIdx.x; i < N_GRAPHS; i += blockDim.x) sc[i] = 0.f;
    __syncthreads();
    const int total = N_NODES * 64;
    for (int t = blockIdx.x * blockDim.x + threadIdx.x; t < total; t += gridDim.x * blockDim.x) {
        int n = t >> 6, d = t & 63;
        int g = batch[n];
        atomicAdd(&sp[g * 64 + d], out2[t]);
        if (d == 0) atomicAdd(&sc[g], 1.0f);
    }
    __syncthreads();
    for (int i = threadIdx.x; i < N_GRAPHS * 64; i += blockDim.x)
        if (sp[i] != 0.f) atomicAdd(&pool[i], sp[i]);
    for (int i = threadIdx.x; i < N_GRAPHS; i += blockDim.x)
        if (sc[i] != 0.f) atomicAdd(&cnt[i], sc[i]);
}

// ---------------------------------------------------------------------------
// Head: out[g,s] = (pool[g,:]/cnt[g]) . wp[s,:] + bp[s]
// ---------------------------------------------------------------------------
__global__ void k_head(const float* __restrict__ pool, const float* __restrict__ cnt,
                       const float* __restrict__ wp, const float* __restrict__ bp,
                       float* __restrict__ out)
{
    int t = threadIdx.x;            // 1024 threads = 64 graphs x 16 outputs
    int g = t >> 4, s = t & 15;
    float c = cnt[g]; if (c < 1.f) c = 1.f;
    float acc = bp[s];
    for (int d = 0; d < 64; ++d) acc += (pool[g * 64 + d] / c) * wp[s * 64 + d];
    out[g * 16 + s] = acc;
}

extern "C" void kernel_launch(void* const* d_in, const int* in_sizes, int n_in,
                              void* d_out, int out_size, void* d_ws, size_t ws_size,
                              hipStream_t stream)
{
    const float* x     = (const float*)d_in[0];
    const int*   ei    = (const int*)  d_in[1];
    const int*   batch = (const int*)  d_in[2];
    const float* w1    = (const float*)d_in[3];
    const float* asr1  = (const float*)d_in[4];
    const float* adr1  = (const float*)d_in[5];
    const float* b1    = (const float*)d_in[6];
    const float* w2    = (const float*)d_in[7];
    const float* asr2  = (const float*)d_in[8];
    const float* adr2  = (const float*)d_in[9];
    const float* b2    = (const float*)d_in[10];
    const float* wp    = (const float*)d_in[11];
    const float* bp    = (const float*)d_in[12];
    float* out = (float*)d_out;

    // Workspace layout (~115 MB)
    float* A    = (float*)d_ws;                 // N*128: h1; later h2 (lower N*64) + out2 (upper N*64)
    float* B    = A + (size_t)N_NODES * 128;    // N*128: out1
    float* as1  = B + (size_t)N_NODES * 128;    // N*2
    float* ad1  = as1 + N_NODES * 2;            // N*2
    float* as2  = ad1 + N_NODES * 2;            // N
    float* ad2  = as2 + N_NODES;                // N
    float* pool = ad2 + N_NODES;                // 64*64
    float* cnt  = pool + N_GRAPHS * 64;         // 64
    int* deg    = (int*)(cnt + N_GRAPHS);       // N
    int* rowptr = deg + N_NODES;                // N+1
    int* pos    = rowptr + N_NODES + 1;         // E_TOT
    int* perm   = pos + E_TOT;                  // E_TOT
    float* h1   = A;
    float* out1 = B;
    float* h2   = A;                            // overlays dead h1
    float* out2 = A + (size_t)N_NODES * 64;     // upper half of A

    hipMemsetAsync(deg, 0, (size_t)N_NODES * sizeof(int), stream);
    hipMemsetAsync(pool, 0, (size_t)(N_GRAPHS * 64 + N_GRAPHS) * sizeof(float), stream);

    // Layer-1 projection + attention coefficients
    k_h1<<<(N_NODES * 128) / 256, 256, 0, stream>>>(x, w1, asr1, adr1, h1, as1, ad1);

    // CSR by destination
    const int eb = (E_TOT + 255) / 256;
    k_count<<<eb, 256, 0, stream>>>(ei, deg, pos);
    const int nb1 = (N_NODES + 255) / 256;      // 391
    k_scan1<<<nb1, 256, 0, stream>>>(deg, rowptr, perm);  // perm reused as bsum scratch
    k_scan2<<<1, 512, 0, stream>>>(perm, nb1);
    k_scan3<<<nb1, 256, 0, stream>>>(rowptr, perm);
    k_scatter<<<eb, 256, 0, stream>>>(ei, rowptr, pos, perm);

    // Layer 1 aggregate + ELU
    k_gather1<<<N_NODES, 128, 0, stream>>>(ei, rowptr, perm, h1, as1, ad1, b1, out1);

    // Layer-2 projection + attention coefficients
    k_h2<<<(N_NODES * 64) / 256, 256, 0, stream>>>(out1, w2, asr2, adr2, h2, as2, ad2);

    // Layer 2 aggregate + ELU
    k_gather2<<<N_NODES, 64, 0, stream>>>(ei, rowptr, perm, h2, as2, ad2, b2, out2);

    // Mean pool + head
    k_pool<<<512, 256, 0, stream>>>(out2, batch, pool, cnt);
    k_head<<<1, 1024, 0, stream>>>(pool, cnt, wp, bp, out);
}

// Round 2
// 486.515 us; speedup vs baseline: 1.8837x; 1.8837x over previous
//
#include <hip/hip_runtime.h>

#define N_NODES  100000
#define N_EDGES  1000000
#define E_TOT    1100000   // edges + self-loops
#define N_GRAPHS 64

__device__ __forceinline__ float elu_f(float v) {
    return v > 0.f ? v : expm1f(v);
}

__device__ __forceinline__ float lrelu(float v) {
    return v > 0.f ? v : 0.2f * v;
}

// ---------------------------------------------------------------------------
// K1: h1[n,c] = x[n,:4] . W1[c,:4]  (c = head*64+d, 128 cols)
//     as1[n,h] = sum_d h1[n,h,d]*att_src1[h,d];  ad1 likewise
// ---------------------------------------------------------------------------
__global__ void k_h1(const float* __restrict__ x, const float* __restrict__ w1,
                     const float* __restrict__ asrc, const float* __restrict__ adst,
                     float* __restrict__ h1, float* __restrict__ as1, float* __restrict__ ad1)
{
    __shared__ __align__(16) float sw[128 * 4];
    __shared__ float ssrc[128], sdst[128];
    for (int i = threadIdx.x; i < 512; i += blockDim.x) sw[i] = w1[i];
    for (int i = threadIdx.x; i < 128; i += blockDim.x) { ssrc[i] = asrc[i]; sdst[i] = adst[i]; }
    __syncthreads();

    int t = blockIdx.x * blockDim.x + threadIdx.x;   // grid sized exactly N*128
    int n = t >> 7, c = t & 127;
    const float4 xv = ((const float4*)x)[n];
    const float4 wv = ((const float4*)sw)[c];
    float h = xv.x * wv.x + xv.y * wv.y + xv.z * wv.z + xv.w * wv.w;
    h1[t] = h;

    float ps = h * ssrc[c];
    float pd = h * sdst[c];
    #pragma unroll
    for (int off = 32; off >= 1; off >>= 1) {
        ps += __shfl_xor(ps, off, 64);
        pd += __shfl_xor(pd, off, 64);
    }
    if ((c & 63) == 0) {
        int head = c >> 6;
        as1[n * 2 + head] = ps;
        ad1[n * 2 + head] = pd;
    }
}

// ---------------------------------------------------------------------------
// CSR build: count (with position capture), scan, scatter
// ---------------------------------------------------------------------------
__global__ void k_count(const int* __restrict__ ei, int* __restrict__ deg, int* __restrict__ pos)
{
    int e = blockIdx.x * blockDim.x + threadIdx.x;
    if (e >= E_TOT) return;
    int dst = (e < N_EDGES) ? ei[N_EDGES + e] : (e - N_EDGES);
    pos[e] = atomicAdd(&deg[dst], 1);
}

__global__ void k_scan1(const int* __restrict__ deg, int* __restrict__ ex, int* __restrict__ bsum)
{
    __shared__ int sh[256];
    int tid = threadIdx.x;
    int i = blockIdx.x * 256 + tid;
    int v = (i < N_NODES) ? deg[i] : 0;
    int acc = v;
    sh[tid] = acc; __syncthreads();
    for (int off = 1; off < 256; off <<= 1) {
        int add = (tid >= off) ? sh[tid - off] : 0;
        __syncthreads();
        acc += add;
        sh[tid] = acc;
        __syncthreads();
    }
    if (i < N_NODES) ex[i] = acc - v;          // block-local exclusive
    if (tid == 255) bsum[blockIdx.x] = acc;    // block total
}

__global__ void k_scan2(int* __restrict__ bsum, int nb)
{
    __shared__ int sh[512];
    int tid = threadIdx.x;
    int v = (tid < nb) ? bsum[tid] : 0;
    int acc = v;
    sh[tid] = acc; __syncthreads();
    for (int off = 1; off < 512; off <<= 1) {
        int add = (tid >= off) ? sh[tid - off] : 0;
        __syncthreads();
        acc += add;
        sh[tid] = acc;
        __syncthreads();
    }
    if (tid < nb) bsum[tid] = acc - v;         // exclusive block offsets
}

__global__ void k_scan3(int* __restrict__ rowptr, const int* __restrict__ bsum)
{
    int i = blockIdx.x * 256 + threadIdx.x;
    if (i < N_NODES) rowptr[i] += bsum[blockIdx.x];
    if (i == 0) rowptr[N_NODES] = E_TOT;
}

// scatter: write src node id at CSR slot; convert pos[e] -> absolute CSR index
__global__ void k_scatter(const int* __restrict__ ei, const int* __restrict__ rowptr,
                          int* __restrict__ pos, int* __restrict__ srcs)
{
    int e = blockIdx.x * blockDim.x + threadIdx.x;
    if (e >= E_TOT) return;
    int src = (e < N_EDGES) ? ei[e] : (e - N_EDGES);
    int dst = (e < N_EDGES) ? ei[N_EDGES + e] : (e - N_EDGES);
    int j = rowptr[dst] + pos[e];
    srcs[j] = src;
    pos[e] = j;          // jidx for the weights kernels
}

// ---------------------------------------------------------------------------
// Per-edge softmax numerators, written in CSR order (coalesced gather later)
// ---------------------------------------------------------------------------
__global__ void k_weights1(const int* __restrict__ ei, const int* __restrict__ jidx,
                           const float* __restrict__ as1, const float* __restrict__ ad1,
                           float* __restrict__ wcsr)
{
    int e = blockIdx.x * blockDim.x + threadIdx.x;
    if (e >= E_TOT) return;
    int src = (e < N_EDGES) ? ei[e] : (e - N_EDGES);
    int dst = (e < N_EDGES) ? ei[N_EDGES + e] : (e - N_EDGES);
    float2 s = ((const float2*)as1)[src];
    float2 d = ((const float2*)ad1)[dst];
    float w0 = __expf(lrelu(s.x + d.x));
    float w1 = __expf(lrelu(s.y + d.y));
    ((float2*)wcsr)[jidx[e]] = make_float2(w0, w1);
}

__global__ void k_weights2(const int* __restrict__ ei, const int* __restrict__ jidx,
                           const float* __restrict__ as2, const float* __restrict__ ad2,
                           float* __restrict__ wcsr2)
{
    int e = blockIdx.x * blockDim.x + threadIdx.x;
    if (e >= E_TOT) return;
    int src = (e < N_EDGES) ? ei[e] : (e - N_EDGES);
    int dst = (e < N_EDGES) ? ei[N_EDGES + e] : (e - N_EDGES);
    wcsr2[jidx[e]] = __expf(lrelu(as2[src] + ad2[dst]));
}

// ---------------------------------------------------------------------------
// Gather layer 1: block = 128 threads per node (2 heads x 64 dims)
// inner loop: sequential srcs/wcsr reads (uniform) + one coalesced 512B row
// ---------------------------------------------------------------------------
__global__ void __launch_bounds__(128) k_gather1(
    const int* __restrict__ srcs, const int* __restrict__ rowptr,
    const float* __restrict__ wcsr,
    const float* __restrict__ h1, const float* __restrict__ b1, float* __restrict__ out1)
{
    int n = blockIdx.x;
    int c = threadIdx.x;
    int head = c >> 6;
    int beg = rowptr[n], end = rowptr[n + 1];
    float acc = 0.f, wsum = 0.f;
    for (int j = beg; j < end; ++j) {
        int s = srcs[j];
        float w = wcsr[j * 2 + head];
        wsum += w;
        acc  += w * h1[s * 128 + c];
    }
    out1[n * 128 + c] = elu_f(acc / wsum + b1[c]);
}

// ---------------------------------------------------------------------------
// k_h2 v2: 64 nodes/block, register-blocked 4 nodes x 4 dims per thread.
// W2^T staged with CONFLICT-FREE linear LDS writes (transposed global reads,
// L1/L2-resident); out1 rows staged coalesced. Inner loop: broadcast srow
// reads + contiguous w2t float4 reads -> ~0 bank conflicts.
// ---------------------------------------------------------------------------
#define H2_NPB 64
__global__ void __launch_bounds__(256) k_h2(
    const float* __restrict__ out1, const float* __restrict__ w2,
    const float* __restrict__ asrc, const float* __restrict__ adst,
    float* __restrict__ h2, float* __restrict__ as2, float* __restrict__ ad2)
{
    __shared__ __align__(16) float w2t[128 * 64];       // [k][d]  32 KB
    __shared__ __align__(16) float srow[H2_NPB * 128];  // 64 rows 32 KB
    const int tid = threadIdx.x;
    const int blockNode = blockIdx.x * H2_NPB;

    // stage W2^T: consecutive lanes -> consecutive LDS words (conflict-free);
    // global reads strided but w2 is 32KB, L1-cached after first lines
    for (int i = tid; i < 128 * 64; i += 256) {
        int k = i >> 6, d = i & 63;
        w2t[i] = w2[d * 128 + k];
    }
    // stage out1 rows, coalesced
    for (int i = tid; i < H2_NPB * 128; i += 256)
        srow[i] = out1[(size_t)blockNode * 128 + i];
    __syncthreads();

    const int lane = tid & 63;
    const int wv   = tid >> 6;           // wave id 0..3
    const int q    = lane >> 4;          // node quad within wave
    const int dg   = lane & 15;          // dim group
    const int d_base    = dg * 4;
    const int node_base = wv * 16 + q * 4;

    float4 acc[4] = {{0,0,0,0},{0,0,0,0},{0,0,0,0},{0,0,0,0}};
    for (int k = 0; k < 128; k += 4) {
        const float4 w0 = *(const float4*)&w2t[(k + 0) * 64 + d_base];
        const float4 w1 = *(const float4*)&w2t[(k + 1) * 64 + d_base];
        const float4 wq = *(const float4*)&w2t[(k + 2) * 64 + d_base];
        const float4 w3 = *(const float4*)&w2t[(k + 3) * 64 + d_base];
        #pragma unroll
        for (int j = 0; j < 4; ++j) {
            const float4 rv = *(const float4*)&srow[(node_base + j) * 128 + k];
            acc[j].x += rv.x * w0.x + rv.y * w1.x + rv.z * wq.x + rv.w * w3.x;
            acc[j].y += rv.x * w0.y + rv.y * w1.y + rv.z * wq.y + rv.w * w3.y;
            acc[j].z += rv.x * w0.z + rv.y * w1.z + rv.z * wq.z + rv.w * w3.z;
            acc[j].w += rv.x * w0.w + rv.y * w1.w + rv.z * wq.w + rv.w * w3.w;
        }
    }

    const float4 av = ((const float4*)asrc)[dg];
    const float4 dv = ((const float4*)adst)[dg];
    #pragma unroll
    for (int j = 0; j < 4; ++j) {
        int n = blockNode + node_base + j;
        float ps = acc[j].x * av.x + acc[j].y * av.y + acc[j].z * av.z + acc[j].w * av.w;
        float pd = acc[j].x * dv.x + acc[j].y * dv.y + acc[j].z * dv.z + acc[j].w * dv.w;
        #pragma unroll
        for (int off = 8; off >= 1; off >>= 1) {   // reduce across the 16 dim-groups
            ps += __shfl_xor(ps, off, 64);
            pd += __shfl_xor(pd, off, 64);
        }
        if (n < N_NODES) {
            ((float4*)h2)[((size_t)n * 64 + d_base) >> 2] = acc[j];
            if (dg == 0) { as2[n] = ps; ad2[n] = pd; }
        }
    }
}

// ---------------------------------------------------------------------------
// Gather layer 2: 1 wave per node (64 dims, 1 head)
// ---------------------------------------------------------------------------
__global__ void __launch_bounds__(64) k_gather2(
    const int* __restrict__ srcs, const int* __restrict__ rowptr,
    const float* __restrict__ wcsr2,
    const float* __restrict__ h2, const float* __restrict__ b2, float* __restrict__ out2)
{
    int n = blockIdx.x, d = threadIdx.x;
    int beg = rowptr[n], end = rowptr[n + 1];
    float acc = 0.f, wsum = 0.f;
    for (int j = beg; j < end; ++j) {
        int s = srcs[j];
        float w = wcsr2[j];
        wsum += w;
        acc  += w * h2[s * 64 + d];
    }
    out2[n * 64 + d] = elu_f(acc / wsum + b2[d]);
}

// ---------------------------------------------------------------------------
// Global mean pool: LDS partial sums per block, then few global atomics
// ---------------------------------------------------------------------------
__global__ void k_pool(const float* __restrict__ out2, const int* __restrict__ batch,
                       float* __restrict__ pool, float* __restrict__ cnt)
{
    __shared__ float sp[N_GRAPHS * 64];
    __shared__ float sc[N_GRAPHS];
    for (int i = threadIdx.x; i < N_GRAPHS * 64; i += blockDim.x) sp[i] = 0.f;
    for (int i = threadIdx.x; i < N_GRAPHS; i += blockDim.x) sc[i] = 0.f;
    __syncthreads();
    const int total = N_NODES * 64;
    for (int t = blockIdx.x * blockDim.x + threadIdx.x; t < total; t += gridDim.x * blockDim.x) {
        int n = t >> 6, d = t & 63;
        int g = batch[n];
        atomicAdd(&sp[g * 64 + d], out2[t]);
        if (d == 0) atomicAdd(&sc[g], 1.0f);
    }
    __syncthreads();
    for (int i = threadIdx.x; i < N_GRAPHS * 64; i += blockDim.x)
        if (sp[i] != 0.f) atomicAdd(&pool[i], sp[i]);
    for (int i = threadIdx.x; i < N_GRAPHS; i += blockDim.x)
        if (sc[i] != 0.f) atomicAdd(&cnt[i], sc[i]);
}

// ---------------------------------------------------------------------------
// Head: out[g,s] = (pool[g,:]/cnt[g]) . wp[s,:] + bp[s]
// ---------------------------------------------------------------------------
__global__ void k_head(const float* __restrict__ pool, const float* __restrict__ cnt,
                       const float* __restrict__ wp, const float* __restrict__ bp,
                       float* __restrict__ out)
{
    int t = threadIdx.x;            // 1024 threads = 64 graphs x 16 outputs
    int g = t >> 4, s = t & 15;
    float c = cnt[g]; if (c < 1.f) c = 1.f;
    float acc = bp[s];
    for (int d = 0; d < 64; ++d) acc += (pool[g * 64 + d] / c) * wp[s * 64 + d];
    out[g * 16 + s] = acc;
}

extern "C" void kernel_launch(void* const* d_in, const int* in_sizes, int n_in,
                              void* d_out, int out_size, void* d_ws, size_t ws_size,
                              hipStream_t stream)
{
    const float* x     = (const float*)d_in[0];
    const int*   ei    = (const int*)  d_in[1];
    const int*   batch = (const int*)  d_in[2];
    const float* w1    = (const float*)d_in[3];
    const float* asr1  = (const float*)d_in[4];
    const float* adr1  = (const float*)d_in[5];
    const float* b1    = (const float*)d_in[6];
    const float* w2    = (const float*)d_in[7];
    const float* asr2  = (const float*)d_in[8];
    const float* adr2  = (const float*)d_in[9];
    const float* b2    = (const float*)d_in[10];
    const float* wp    = (const float*)d_in[11];
    const float* bp    = (const float*)d_in[12];
    float* out = (float*)d_out;

    // Workspace layout (~123 MB)
    float* A    = (float*)d_ws;                 // N*128: h1; later h2 (lower N*64) + out2 (upper N*64)
    float* B    = A + (size_t)N_NODES * 128;    // N*128: out1
    float* as1  = B + (size_t)N_NODES * 128;    // N*2
    float* ad1  = as1 + N_NODES * 2;            // N*2
    float* as2  = ad1 + N_NODES * 2;            // N
    float* ad2  = as2 + N_NODES;                // N
    float* pool = ad2 + N_NODES;                // 64*64
    float* cnt  = pool + N_GRAPHS * 64;         // 64
    int* deg    = (int*)(cnt + N_GRAPHS);       // N
    int* rowptr = deg + N_NODES;                // N+1
    int* pos    = rowptr + N_NODES + 1;         // E_TOT (count pos, then jidx)
    int* srcs   = pos + E_TOT;                  // E_TOT (also scan bsum scratch)
    float* wcsr = (float*)(srcs + E_TOT);       // E_TOT*2 (layer1); layer2 aliases
    float* h1   = A;
    float* out1 = B;
    float* h2   = A;                            // overlays dead h1
    float* out2 = A + (size_t)N_NODES * 64;     // upper half of A

    hipMemsetAsync(deg, 0, (size_t)N_NODES * sizeof(int), stream);
    hipMemsetAsync(pool, 0, (size_t)(N_GRAPHS * 64 + N_GRAPHS) * sizeof(float), stream);

    // Layer-1 projection + attention coefficients
    k_h1<<<(N_NODES * 128) / 256, 256, 0, stream>>>(x, w1, asr1, adr1, h1, as1, ad1);

    // CSR by destination (srcs doubles as scan block-sum scratch before scatter)
    const int eb = (E_TOT + 255) / 256;
    k_count<<<eb, 256, 0, stream>>>(ei, deg, pos);
    const int nb1 = (N_NODES + 255) / 256;      // 391
    k_scan1<<<nb1, 256, 0, stream>>>(deg, rowptr, srcs);
    k_scan2<<<1, 512, 0, stream>>>(srcs, nb1);
    k_scan3<<<nb1, 256, 0, stream>>>(rowptr, srcs);
    k_scatter<<<eb, 256, 0, stream>>>(ei, rowptr, pos, srcs);

    // Layer-1 edge weights (CSR order) + aggregate + ELU
    k_weights1<<<eb, 256, 0, stream>>>(ei, pos, as1, ad1, wcsr);
    k_gather1<<<N_NODES, 128, 0, stream>>>(srcs, rowptr, wcsr, h1, b1, out1);

    // Layer-2 projection + attention coefficients
    k_h2<<<(N_NODES + H2_NPB - 1) / H2_NPB, 256, 0, stream>>>(out1, w2, adr2 ? asr2 : asr2, adr2, h2, as2, ad2);

    // Layer-2 edge weights + aggregate + ELU  (wcsr2 aliases wcsr, dead after gather1)
    float* wcsr2 = wcsr;
    k_weights2<<<eb, 256, 0, stream>>>(ei, pos, as2, ad2, wcsr2);
    k_gather2<<<N_NODES, 64, 0, stream>>>(srcs, rowptr, wcsr2, h2, b2, out2);

    // Mean pool + head
    k_pool<<<512, 256, 0, stream>>>(out2, batch, pool, cnt);
    k_head<<<1, 1024, 0, stream>>>(pool, cnt, wp, bp, out);
}

// Round 3
// 341.848 us; speedup vs baseline: 2.6808x; 1.4232x over previous
//
#include <hip/hip_runtime.h>
#include <hip/hip_fp16.h>

#define N_NODES  100000
#define N_EDGES  1000000
#define E_TOT    1100000   // edges + self-loops
#define N_GRAPHS 64

__device__ __forceinline__ float elu_f(float v) {
    return v > 0.f ? v : expm1f(v);
}

__device__ __forceinline__ float lrelu(float v) {
    return v > 0.f ? v : 0.2f * v;
}

// ---------------------------------------------------------------------------
// K1: h1[n,c] = x[n,:4] . W1[c,:4]  (c = head*64+d, 128 cols), h1 stored fp16
//     as1[n,h] = sum_d h1[n,h,d]*att_src1[h,d];  ad1 likewise (f32)
// ---------------------------------------------------------------------------
__global__ void k_h1(const float* __restrict__ x, const float* __restrict__ w1,
                     const float* __restrict__ asrc, const float* __restrict__ adst,
                     __half* __restrict__ h1h, float* __restrict__ as1, float* __restrict__ ad1)
{
    __shared__ __align__(16) float sw[128 * 4];
    __shared__ float ssrc[128], sdst[128];
    for (int i = threadIdx.x; i < 512; i += blockDim.x) sw[i] = w1[i];
    for (int i = threadIdx.x; i < 128; i += blockDim.x) { ssrc[i] = asrc[i]; sdst[i] = adst[i]; }
    __syncthreads();

    int t = blockIdx.x * blockDim.x + threadIdx.x;   // grid sized exactly N*128
    int n = t >> 7, c = t & 127;
    const float4 xv = ((const float4*)x)[n];
    const float4 wv = ((const float4*)sw)[c];
    float h = xv.x * wv.x + xv.y * wv.y + xv.z * wv.z + xv.w * wv.w;
    h1h[t] = __float2half(h);

    float ps = h * ssrc[c];
    float pd = h * sdst[c];
    #pragma unroll
    for (int off = 32; off >= 1; off >>= 1) {
        ps += __shfl_xor(ps, off, 64);
        pd += __shfl_xor(pd, off, 64);
    }
    if ((c & 63) == 0) {
        int head = c >> 6;
        as1[n * 2 + head] = ps;
        ad1[n * 2 + head] = pd;
    }
}

// ---------------------------------------------------------------------------
// CSR build: count (with position capture), scan, scatter
// ---------------------------------------------------------------------------
__global__ void k_count(const int* __restrict__ ei, int* __restrict__ deg, int* __restrict__ pos)
{
    int e = blockIdx.x * blockDim.x + threadIdx.x;
    if (e >= E_TOT) return;
    int dst = (e < N_EDGES) ? ei[N_EDGES + e] : (e - N_EDGES);
    pos[e] = atomicAdd(&deg[dst], 1);
}

__global__ void k_scan1(const int* __restrict__ deg, int* __restrict__ ex, int* __restrict__ bsum)
{
    __shared__ int sh[256];
    int tid = threadIdx.x;
    int i = blockIdx.x * 256 + tid;
    int v = (i < N_NODES) ? deg[i] : 0;
    int acc = v;
    sh[tid] = acc; __syncthreads();
    for (int off = 1; off < 256; off <<= 1) {
        int add = (tid >= off) ? sh[tid - off] : 0;
        __syncthreads();
        acc += add;
        sh[tid] = acc;
        __syncthreads();
    }
    if (i < N_NODES) ex[i] = acc - v;          // block-local exclusive
    if (tid == 255) bsum[blockIdx.x] = acc;    // block total
}

__global__ void k_scan2(int* __restrict__ bsum, int nb)
{
    __shared__ int sh[512];
    int tid = threadIdx.x;
    int v = (tid < nb) ? bsum[tid] : 0;
    int acc = v;
    sh[tid] = acc; __syncthreads();
    for (int off = 1; off < 512; off <<= 1) {
        int add = (tid >= off) ? sh[tid - off] : 0;
        __syncthreads();
        acc += add;
        sh[tid] = acc;
        __syncthreads();
    }
    if (tid < nb) bsum[tid] = acc - v;         // exclusive block offsets
}

__global__ void k_scan3(int* __restrict__ rowptr, const int* __restrict__ bsum)
{
    int i = blockIdx.x * 256 + threadIdx.x;
    if (i < N_NODES) rowptr[i] += bsum[blockIdx.x];
    if (i == 0) rowptr[N_NODES] = E_TOT;
}

__global__ void k_scatter(const int* __restrict__ ei, const int* __restrict__ rowptr,
                          const int* __restrict__ pos, int* __restrict__ srcs)
{
    int e = blockIdx.x * blockDim.x + threadIdx.x;
    if (e >= E_TOT) return;
    int src = (e < N_EDGES) ? ei[e] : (e - N_EDGES);
    int dst = (e < N_EDGES) ? ei[N_EDGES + e] : (e - N_EDGES);
    srcs[rowptr[dst] + pos[e]] = src;
}

// ---------------------------------------------------------------------------
// Gather layer 1: 4 nodes/block, one wave per node. Lane l holds dims (2l,2l+1)
// via __half2; head = l>>5. Weight computed inline; clamped unroll-4 keeps
// 4 edges' loads in flight.
// ---------------------------------------------------------------------------
__global__ void __launch_bounds__(256) k_gather1(
    const int* __restrict__ srcs, const int* __restrict__ rowptr,
    const float* __restrict__ as1, const float* __restrict__ ad1,
    const __half* __restrict__ h1h, const float* __restrict__ b1,
    float* __restrict__ out1)
{
    const int tid  = threadIdx.x;
    const int n    = blockIdx.x * 4 + (tid >> 6);
    const int l    = tid & 63;
    const int head = l >> 5;
    if (n >= N_NODES) return;
    const int beg = rowptr[n], end = rowptr[n + 1];
    const float adv = ad1[n * 2 + head];
    const __half2* __restrict__ h1v = (const __half2*)h1h;

    float2 acc = {0.f, 0.f};
    float wsum = 0.f;
    for (int j = beg; j < end; j += 4) {
        int j1 = min(j + 1, end - 1);
        int j2 = min(j + 2, end - 1);
        int j3 = min(j + 3, end - 1);
        int s0 = srcs[j],  s1 = srcs[j1], s2 = srcs[j2], s3 = srcs[j3];
        float a0 = as1[s0 * 2 + head];
        float a1 = as1[s1 * 2 + head];
        float a2 = as1[s2 * 2 + head];
        float a3 = as1[s3 * 2 + head];
        float2 v0 = __half22float2(h1v[(size_t)s0 * 64 + l]);
        float2 v1 = __half22float2(h1v[(size_t)s1 * 64 + l]);
        float2 v2 = __half22float2(h1v[(size_t)s2 * 64 + l]);
        float2 v3 = __half22float2(h1v[(size_t)s3 * 64 + l]);
        float w0 = __expf(lrelu(a0 + adv));
        float w1 = (j + 1 < end) ? __expf(lrelu(a1 + adv)) : 0.f;
        float w2 = (j + 2 < end) ? __expf(lrelu(a2 + adv)) : 0.f;
        float w3 = (j + 3 < end) ? __expf(lrelu(a3 + adv)) : 0.f;
        wsum  += (w0 + w1) + (w2 + w3);
        acc.x += w0 * v0.x + w1 * v1.x + w2 * v2.x + w3 * v3.x;
        acc.y += w0 * v0.y + w1 * v1.y + w2 * v2.y + w3 * v3.y;
    }
    const float2 bv = ((const float2*)b1)[l];
    float2 o;
    o.x = elu_f(acc.x / wsum + bv.x);
    o.y = elu_f(acc.y / wsum + bv.y);
    ((float2*)out1)[(size_t)n * 64 + l] = o;
}

// ---------------------------------------------------------------------------
// k_h2: 64 nodes/block, register-blocked 4 nodes x 4 dims per thread.
// W2^T staged conflict-free; srow padded to stride 132 (kills 4-way read
// conflict). Writes h2 as fp16; as2/ad2 in f32.
// ---------------------------------------------------------------------------
#define H2_NPB 64
#define SROW_LD 132
__global__ void __launch_bounds__(256) k_h2(
    const float* __restrict__ out1, const float* __restrict__ w2,
    const float* __restrict__ asrc, const float* __restrict__ adst,
    __half* __restrict__ h2h, float* __restrict__ as2, float* __restrict__ ad2)
{
    __shared__ __align__(16) float w2t[128 * 64];          // [k][d]  32 KB
    __shared__ __align__(16) float srow[H2_NPB * SROW_LD]; // 64 rows, padded
    const int tid = threadIdx.x;
    const int blockNode = blockIdx.x * H2_NPB;

    for (int i = tid; i < 128 * 64; i += 256) {
        int k = i >> 6, d = i & 63;
        w2t[i] = w2[d * 128 + k];
    }
    for (int i = tid; i < H2_NPB * 128; i += 256) {
        int r = i >> 7, col = i & 127;
        srow[r * SROW_LD + col] = out1[(size_t)blockNode * 128 + i];
    }
    __syncthreads();

    const int lane = tid & 63;
    const int wv   = tid >> 6;           // wave id 0..3
    const int q    = lane >> 4;          // node quad within wave
    const int dg   = lane & 15;          // dim group
    const int d_base    = dg * 4;
    const int node_base = wv * 16 + q * 4;

    float4 acc[4] = {{0,0,0,0},{0,0,0,0},{0,0,0,0},{0,0,0,0}};
    for (int k = 0; k < 128; k += 4) {
        const float4 w0 = *(const float4*)&w2t[(k + 0) * 64 + d_base];
        const float4 w1 = *(const float4*)&w2t[(k + 1) * 64 + d_base];
        const float4 wq = *(const float4*)&w2t[(k + 2) * 64 + d_base];
        const float4 w3 = *(const float4*)&w2t[(k + 3) * 64 + d_base];
        #pragma unroll
        for (int j = 0; j < 4; ++j) {
            const float4 rv = *(const float4*)&srow[(node_base + j) * SROW_LD + k];
            acc[j].x += rv.x * w0.x + rv.y * w1.x + rv.z * wq.x + rv.w * w3.x;
            acc[j].y += rv.x * w0.y + rv.y * w1.y + rv.z * wq.y + rv.w * w3.y;
            acc[j].z += rv.x * w0.z + rv.y * w1.z + rv.z * wq.z + rv.w * w3.z;
            acc[j].w += rv.x * w0.w + rv.y * w1.w + rv.z * wq.w + rv.w * w3.w;
        }
    }

    const float4 av = ((const float4*)asrc)[dg];
    const float4 dv = ((const float4*)adst)[dg];
    #pragma unroll
    for (int j = 0; j < 4; ++j) {
        int n = blockNode + node_base + j;
        float ps = acc[j].x * av.x + acc[j].y * av.y + acc[j].z * av.z + acc[j].w * av.w;
        float pd = acc[j].x * dv.x + acc[j].y * dv.y + acc[j].z * dv.z + acc[j].w * dv.w;
        #pragma unroll
        for (int off = 8; off >= 1; off >>= 1) {   // reduce across the 16 dim-groups
            ps += __shfl_xor(ps, off, 64);
            pd += __shfl_xor(pd, off, 64);
        }
        if (n < N_NODES) {
            __half2 p0 = __floats2half2_rn(acc[j].x, acc[j].y);
            __half2 p1 = __floats2half2_rn(acc[j].z, acc[j].w);
            ((__half2*)h2h)[(size_t)n * 32 + dg * 2]     = p0;
            ((__half2*)h2h)[(size_t)n * 32 + dg * 2 + 1] = p1;
            if (dg == 0) { as2[n] = ps; ad2[n] = pd; }
        }
    }
}

// ---------------------------------------------------------------------------
// Gather layer 2: 4 nodes/block, wave per node, lane d holds dim d (fp16 row)
// ---------------------------------------------------------------------------
__global__ void __launch_bounds__(256) k_gather2(
    const int* __restrict__ srcs, const int* __restrict__ rowptr,
    const float* __restrict__ as2, const float* __restrict__ ad2,
    const __half* __restrict__ h2h, const float* __restrict__ b2,
    float* __restrict__ out2)
{
    const int tid = threadIdx.x;
    const int n   = blockIdx.x * 4 + (tid >> 6);
    const int d   = tid & 63;
    if (n >= N_NODES) return;
    const int beg = rowptr[n], end = rowptr[n + 1];
    const float adv = ad2[n];

    float acc = 0.f, wsum = 0.f;
    for (int j = beg; j < end; j += 4) {
        int j1 = min(j + 1, end - 1);
        int j2 = min(j + 2, end - 1);
        int j3 = min(j + 3, end - 1);
        int s0 = srcs[j],  s1 = srcs[j1], s2 = srcs[j2], s3 = srcs[j3];
        float a0 = as2[s0], a1 = as2[s1], a2 = as2[s2], a3 = as2[s3];
        float v0 = __half2float(h2h[(size_t)s0 * 64 + d]);
        float v1 = __half2float(h2h[(size_t)s1 * 64 + d]);
        float v2 = __half2float(h2h[(size_t)s2 * 64 + d]);
        float v3 = __half2float(h2h[(size_t)s3 * 64 + d]);
        float w0 = __expf(lrelu(a0 + adv));
        float w1 = (j + 1 < end) ? __expf(lrelu(a1 + adv)) : 0.f;
        float w2 = (j + 2 < end) ? __expf(lrelu(a2 + adv)) : 0.f;
        float w3 = (j + 3 < end) ? __expf(lrelu(a3 + adv)) : 0.f;
        wsum += (w0 + w1) + (w2 + w3);
        acc  += w0 * v0 + w1 * v1 + w2 * v2 + w3 * v3;
    }
    out2[(size_t)n * 64 + d] = elu_f(acc / wsum + b2[d]);
}

// ---------------------------------------------------------------------------
// Global mean pool: batch is sorted, so accumulate in registers per wave-range
// and flush at graph boundaries (few global atomics).
// ---------------------------------------------------------------------------
__global__ void __launch_bounds__(256) k_pool(
    const float* __restrict__ out2, const int* __restrict__ batch,
    float* __restrict__ pool, float* __restrict__ cnt)
{
    const int wv = threadIdx.x >> 6, d = threadIdx.x & 63;
    const int wid = blockIdx.x * 4 + wv;               // 2048 wave ranges
    const int per = (N_NODES + 2047) / 2048;           // 49
    int n0 = wid * per, n1 = min(n0 + per, N_NODES);
    if (n0 >= n1) return;
    float acc = 0.f; int g = batch[n0]; int run = 0;
    for (int n = n0; n < n1; ++n) {
        int gn = batch[n];
        if (gn != g) {
            atomicAdd(&pool[g * 64 + d], acc);
            if (d == 0) atomicAdd(&cnt[g], (float)run);
            acc = 0.f; run = 0; g = gn;
        }
        acc += out2[(size_t)n * 64 + d];
        ++run;
    }
    atomicAdd(&pool[g * 64 + d], acc);
    if (d == 0) atomicAdd(&cnt[g], (float)run);
}

// ---------------------------------------------------------------------------
// Head: out[g,s] = (pool[g,:]/cnt[g]) . wp[s,:] + bp[s]
// ---------------------------------------------------------------------------
__global__ void k_head(const float* __restrict__ pool, const float* __restrict__ cnt,
                       const float* __restrict__ wp, const float* __restrict__ bp,
                       float* __restrict__ out)
{
    int t = threadIdx.x;            // 1024 threads = 64 graphs x 16 outputs
    int g = t >> 4, s = t & 15;
    float c = cnt[g]; if (c < 1.f) c = 1.f;
    float acc = bp[s];
    for (int d = 0; d < 64; ++d) acc += (pool[g * 64 + d] / c) * wp[s * 64 + d];
    out[g * 16 + s] = acc;
}

extern "C" void kernel_launch(void* const* d_in, const int* in_sizes, int n_in,
                              void* d_out, int out_size, void* d_ws, size_t ws_size,
                              hipStream_t stream)
{
    const float* x     = (const float*)d_in[0];
    const int*   ei    = (const int*)  d_in[1];
    const int*   batch = (const int*)  d_in[2];
    const float* w1    = (const float*)d_in[3];
    const float* asr1  = (const float*)d_in[4];
    const float* adr1  = (const float*)d_in[5];
    const float* b1    = (const float*)d_in[6];
    const float* w2    = (const float*)d_in[7];
    const float* asr2  = (const float*)d_in[8];
    const float* adr2  = (const float*)d_in[9];
    const float* b2    = (const float*)d_in[10];
    const float* wp    = (const float*)d_in[11];
    const float* bp    = (const float*)d_in[12];
    float* out = (float*)d_out;

    // Workspace layout (~93 MB)
    __half* h1h = (__half*)d_ws;                       // N*128 fp16; later h2h (N*64) overlays
    float* out1 = (float*)(h1h + (size_t)N_NODES * 128);  // N*128 f32; later out2 (N*64) overlays
    float* as1  = out1 + (size_t)N_NODES * 128;        // N*2
    float* ad1  = as1 + N_NODES * 2;                   // N*2
    float* as2  = ad1 + N_NODES * 2;                   // N
    float* ad2  = as2 + N_NODES;                       // N
    float* pool = ad2 + N_NODES;                       // 64*64
    float* cnt  = pool + N_GRAPHS * 64;                // 64
    int* deg    = (int*)(cnt + N_GRAPHS);              // N
    int* rowptr = deg + N_NODES;                       // N+1
    int* pos    = rowptr + N_NODES + 1;                // E_TOT
    int* srcs   = pos + E_TOT;                         // E_TOT (also scan bsum scratch)
    __half* h2h = h1h;                                 // overlays dead h1h
    float* out2 = out1;                                // overlays dead out1

    hipMemsetAsync(deg, 0, (size_t)N_NODES * sizeof(int), stream);
    hipMemsetAsync(pool, 0, (size_t)(N_GRAPHS * 64 + N_GRAPHS) * sizeof(float), stream);

    // Layer-1 projection + attention coefficients
    k_h1<<<(N_NODES * 128) / 256, 256, 0, stream>>>(x, w1, asr1, adr1, h1h, as1, ad1);

    // CSR by destination (srcs doubles as scan block-sum scratch before scatter)
    const int eb = (E_TOT + 255) / 256;
    k_count<<<eb, 256, 0, stream>>>(ei, deg, pos);
    const int nb1 = (N_NODES + 255) / 256;      // 391
    k_scan1<<<nb1, 256, 0, stream>>>(deg, rowptr, srcs);
    k_scan2<<<1, 512, 0, stream>>>(srcs, nb1);
    k_scan3<<<nb1, 256, 0, stream>>>(rowptr, srcs);
    k_scatter<<<eb, 256, 0, stream>>>(ei, rowptr, pos, srcs);

    // Layer 1 aggregate + ELU (weights inline)
    k_gather1<<<(N_NODES + 3) / 4, 256, 0, stream>>>(srcs, rowptr, as1, ad1, h1h, b1, out1);

    // Layer-2 projection + attention coefficients (writes fp16 h2)
    k_h2<<<(N_NODES + H2_NPB - 1) / H2_NPB, 256, 0, stream>>>(out1, w2, asr2, adr2, h2h, as2, ad2);

    // Layer 2 aggregate + ELU (weights inline)
    k_gather2<<<(N_NODES + 3) / 4, 256, 0, stream>>>(srcs, rowptr, as2, ad2, h2h, b2, out2);

    // Mean pool + head
    k_pool<<<512, 256, 0, stream>>>(out2, batch, pool, cnt);
    k_head<<<1, 1024, 0, stream>>>(pool, cnt, wp, bp, out);
}